// Round 1
// baseline (428.261 us; speedup 1.0000x reference)
//
#include <hip/hip_runtime.h>

// DGMNet fused kernel for MI355X (gfx950) — round 8.
// R7 was VALU-issue-bound (VALUBusy 57% vs MfmaUtil 25%, HBM 3%). R8 attacks
// the VALU op count and the stalls around it:
//  1. Prescale: Sw/Uz/Ug/Ur/Wsz/Wsg/Wsr (+ biases) are pre-multiplied by
//     2*log2(e) in prep, so every gate is exp2(acc)->rcp->fma (no muls inside
//     the activation). H path (Uh/Wsh) stays unscaled. Ws*_b biases are now
//     folded into the u-projection C-init (correct for nonzero biases).
//  2. bf16 packing via native conversion (v_cvt_pk_bf16_f32 from
//     __builtin_convertvector) instead of 7-op manual RNE bit-twiddle.
//  3. Z/G/R gemms share one ds_read per A-fragment (3 MFMAs per read); the 4
//     U-projections fuse the same way. LDS b128 reads per layer: 32 -> 16(+8).
//  4. XOR swizzle (bits 6-8 -> bits 3-5) on all xtb/sb indices: the stride-16B
//     b16 epilogue stores were an 8-way bank conflict (9.8M conflict cycles).
//  5. 2 barriers/layer (was 3): S double-buffered sb0/sb1, S*R in own buffer.
//  6. Wh lives in the spare LDS (object still 64KB -> 2 blocks/CU -> 128-reg
//     RA budget, the R2-R7 mechanism); peak live regs ~112 < 128.

typedef __attribute__((ext_vector_type(8))) short bf16x8;
typedef __attribute__((ext_vector_type(4))) float f32x4;
typedef __attribute__((ext_vector_type(2))) unsigned int u32x2;
typedef __attribute__((ext_vector_type(2))) float f32x2t;
typedef __attribute__((ext_vector_type(2))) __bf16 bf16x2t;

#define HID 128
#define XD 100
#define BROWS 32
#define NMAT 9
#define MATS 16384   // ushorts per 128x128 matrix

#define SC 2.885390081777927f   // 2*log2(e)

#define MFMA(a, b, c) __builtin_amdgcn_mfma_f32_16x16x32_bf16((a), (b), (c), 0, 0, 0)

// ---------- bf16 helpers (native RNE conversion -> v_cvt_pk_bf16_f32) ------
__device__ __forceinline__ unsigned short f2bf(float f) {
    return __builtin_bit_cast(unsigned short, (__bf16)f);
}
__device__ __forceinline__ unsigned pack2(float lo, float hi) {
    bf16x2t h = __builtin_convertvector((f32x2t){lo, hi}, bf16x2t);
    return __builtin_bit_cast(unsigned, h);
}
__device__ __forceinline__ float bf_lo(unsigned p) { return __uint_as_float(p << 16); }
__device__ __forceinline__ float bf_hi(unsigned p) { return __uint_as_float(p & 0xFFFF0000u); }

__device__ __forceinline__ float fexp2(float x) {
#if __has_builtin(__builtin_amdgcn_exp2f)
    return __builtin_amdgcn_exp2f(x);
#else
    return __expf(0.69314718055994531f * x);
#endif
}
// tanh(y) given a = 2*log2e*y
__device__ __forceinline__ float tanh_a(float a) {
    float r = __builtin_amdgcn_rcpf(fexp2(a) + 1.0f);
    return __builtin_fmaf(-2.0f, r, 1.0f);
}
// rcp(exp2(a)+1); 1-tanh(y) = 2*rcp1p(a)
__device__ __forceinline__ float rcp1p(float a) {
    return __builtin_amdgcn_rcpf(fexp2(a) + 1.0f);
}

// ---------- prep: fp32 [K][128] -> bf16 fragment order (coalesced reads) ----
// mats: 0 Sw 1 Uz 2 Ug 3 Ur 4 Uh (K=101, pad to 128) | 5 Wsz 6 Wsg 7 Wsr 8 Wsh
// frag layout: ((ks*8+nt)*64+lane)*8+b <-> W[k=ks*32+(lane>>4)*8+b][n=nt*16+(lane&15)]
// mats feeding a tanh (0,1,2,3,5,6,7) are prescaled by SC.
__global__ void prep_kernel(const float* __restrict__ Sw, const float* __restrict__ Uz,
                            const float* __restrict__ Ug, const float* __restrict__ Ur,
                            const float* __restrict__ Uh, const float* __restrict__ Wsz,
                            const float* __restrict__ Wsg, const float* __restrict__ Wsr,
                            const float* __restrict__ Wsh, unsigned short* __restrict__ out) {
    int g = blockIdx.x * blockDim.x + threadIdx.x;
    if (g >= NMAT * 4096) return;           // 128 k x 32 n-quads per matrix
    int m = g >> 12, r = g & 4095;
    int k = r >> 5, n4 = (r & 31) * 4;
    const float* src; int kmax; float scl;
    switch (m) {
        case 0: src = Sw;  kmax = 101; scl = SC;  break;
        case 1: src = Uz;  kmax = 101; scl = SC;  break;
        case 2: src = Ug;  kmax = 101; scl = SC;  break;
        case 3: src = Ur;  kmax = 101; scl = SC;  break;
        case 4: src = Uh;  kmax = 101; scl = 1.f; break;
        case 5: src = Wsz; kmax = 128; scl = SC;  break;
        case 6: src = Wsg; kmax = 128; scl = SC;  break;
        case 7: src = Wsr; kmax = 128; scl = SC;  break;
        default: src = Wsh; kmax = 128; scl = 1.f; break;
    }
    f32x4 v = (f32x4){0.f, 0.f, 0.f, 0.f};
    if (k < kmax) v = *(const f32x4*)(src + k * HID + n4);
    int ks = k >> 5, b = k & 7, lq = ((k >> 3) & 3) << 4;
    int nt = n4 >> 4;
    size_t mb = (size_t)m * MATS;
    #pragma unroll
    for (int i = 0; i < 4; ++i) {
        int lane = lq | ((n4 + i) & 15);
        out[mb + (size_t)((ks * 8 + nt) * 64 + lane) * 8 + b] = f2bf(v[i] * scl);
    }
}

__device__ __forceinline__ void loadB(const unsigned short* __restrict__ wbuf, int mat,
                                      int nt, int lane, bf16x8 (&B)[4]) {
    #pragma unroll
    for (int ks = 0; ks < 4; ++ks)
        B[ks] = *(const bf16x8*)(wbuf + (size_t)mat * MATS +
                                 ((size_t)((ks * 8 + nt) * 64 + lane)) * 8);
}

// single-B gemm: A (LDS, swizzled frag order) x B (regs); acc pre-initialized
__device__ __forceinline__ void gemm1(const unsigned short* __restrict__ A, int aoff,
                                      const bf16x8 (&B)[4], f32x4 (&acc)[2]) {
    #pragma unroll
    for (int ks = 0; ks < 4; ++ks)
        #pragma unroll
        for (int mt = 0; mt < 2; ++mt) {
            bf16x8 a = *(const bf16x8*)(A + mt * 2048 + ks * 512 + aoff);
            acc[mt] = MFMA(a, B[ks], acc[mt]);
        }
}

// ---------- main ----------
__global__ __launch_bounds__(512, 4)
void dgm_main(const float* __restrict__ x, const float* __restrict__ tptr,
              const unsigned short* __restrict__ wbuf,
              const float* __restrict__ Sw_b, const float* __restrict__ Uz_b,
              const float* __restrict__ Ug_b, const float* __restrict__ Ur_b,
              const float* __restrict__ Uh_b,
              const float* __restrict__ Wsz_b, const float* __restrict__ Wsg_b,
              const float* __restrict__ Wsr_b, const float* __restrict__ Wsh_b,
              const float* __restrict__ Wf_w, const float* __restrict__ Wf_b,
              const int* __restrict__ nlayers, float* __restrict__ y) {
    // ONE 64KB LDS object (occupancy pin: 2 blocks/CU @512thr -> 128-reg RA
    // budget). Views: xtb [0,4096) = xt, later S*R, later y-partials;
    // sb0 [4096,8192); sb1 [8192,12288); whb [12288,28672) = Wh B-frags.
    __shared__ unsigned short lds[32768];
    unsigned short* xtb = lds;
    unsigned short* sb0 = lds + 4096;
    unsigned short* sb1 = lds + 8192;
    unsigned short* whb = lds + 12288;

    const int tid = threadIdx.x;
    const int wv = tid >> 6, lane = tid & 63;
    const int quad = lane >> 4, l15 = lane & 15;
    const int blk = blockIdx.x;
    const int lcount = nlayers[0] - 1;
    const int nt = wv;                       // one 16-col n-tile per wave
    const int col = nt * 16 + l15;

    // A-frag read offset, XOR-swizzled: idx ^= ((idx>>6)&7)<<3
    const int aoff = (lane * 8) ^ (((lane >> 3) & 7) << 3);
    // epilogue b16 store addresses (C-layout -> A-frag positions), same swizzle
    const int sc = (col >> 5) * 512 + ((col >> 3) & 3) * 128 + (col & 7) + quad * 32;
    const int swv = ((((col >> 3) & 3) << 1) | (quad >> 1)) << 3;
    const int st0 = (sc +  0) ^ swv;
    const int st1 = (sc +  8) ^ swv;
    const int st2 = (sc + 16) ^ swv;
    const int st3 = (sc + 24) ^ swv;

    // ---- zero the k>=96 pad frags of xtb (frag ks==3; region closed under
    // the swizzle, so plain dword zeroing is fine), then fill xt ----
    {
        int mt = tid >> 8;
        ((unsigned*)xtb)[mt * 1024 + 768 + (tid & 255)] = 0u;
    }
    __syncthreads();

    {
        const float* xsrc = x + (size_t)blk * BROWS * XD;
        for (int i = tid; i < BROWS * (XD / 4); i += 512) {     // 800 float4s
            int row = i / 25, c4 = i % 25, k0 = c4 * 4;
            f32x4 v = *(const f32x4*)(xsrc + row * XD + k0);
            int idx = (row >> 4) * 2048 + (k0 >> 5) * 512 + ((k0 >> 3) & 3) * 128 +
                      (row & 15) * 8 + (k0 & 7);
            idx ^= ((((k0 >> 3) & 3) << 1) | ((row >> 3) & 1)) << 3;
            *(u32x2*)(xtb + idx) = (u32x2){pack2(v[0], v[1]), pack2(v[2], v[3])};
        }
        if (tid < BROWS) {                                      // t column, k=100
            int idx = (tid >> 4) * 2048 + 3 * 512 + (tid & 15) * 8 + 4;
            idx ^= ((tid >> 3) & 1) << 3;
            xtb[idx] = f2bf(tptr[(size_t)blk * BROWS + tid]);
        }
    }
    __syncthreads();

    f32x4 sreg4[2];       // S (fp32, C-layout)
    unsigned u2[4][2][2]; // pre-biased projections, packed bf16: 0 uz 1 ug 2 ur 3 uh
                          // (z/g/r entries are SC-prescaled; h unscaled)

    // ---- projection phase ----
    {   // S1 = tanh(xt@Sw + b)   (Sw, b prescaled by SC)
        bf16x8 BS[4];
        loadB(wbuf, 0, nt, lane, BS);
        float bv = SC * Sw_b[col];
        f32x4 acc[2];
        acc[0] = (f32x4){bv, bv, bv, bv};
        acc[1] = acc[0];
        gemm1(xtb, aoff, BS, acc);
        #pragma unroll
        for (int mt = 0; mt < 2; ++mt) {
            f32x4 s;
            #pragma unroll
            for (int e = 0; e < 4; ++e)
                s[e] = tanh_a(acc[mt][e]);
            sreg4[mt] = s;
            unsigned p01 = pack2(s[0], s[1]), p23 = pack2(s[2], s[3]);
            sb0[mt * 2048 + st0] = (unsigned short)p01;
            sb0[mt * 2048 + st1] = (unsigned short)(p01 >> 16);
            sb0[mt * 2048 + st2] = (unsigned short)p23;
            sb0[mt * 2048 + st3] = (unsigned short)(p23 >> 16);
        }
    }
    {   // fused u-projections: one A-read feeds 4 MFMAs (Uz,Ug,Ur,Uh)
        bf16x8 BU[4][4];
        #pragma unroll
        for (int mi = 0; mi < 4; ++mi)
            loadB(wbuf, 1 + mi, nt, lane, BU[mi]);
        float bz = SC * (Uz_b[col] + Wsz_b[col]);
        float bg = SC * (Ug_b[col] + Wsg_b[col]);
        float br = SC * (Ur_b[col] + Wsr_b[col]);
        float bh = Uh_b[col] + Wsh_b[col];
        f32x4 aU[4][2];
        aU[0][0] = (f32x4){bz, bz, bz, bz}; aU[0][1] = aU[0][0];
        aU[1][0] = (f32x4){bg, bg, bg, bg}; aU[1][1] = aU[1][0];
        aU[2][0] = (f32x4){br, br, br, br}; aU[2][1] = aU[2][0];
        aU[3][0] = (f32x4){bh, bh, bh, bh}; aU[3][1] = aU[3][0];
        #pragma unroll
        for (int ks = 0; ks < 4; ++ks)
            #pragma unroll
            for (int mt = 0; mt < 2; ++mt) {
                bf16x8 a = *(const bf16x8*)(xtb + mt * 2048 + ks * 512 + aoff);
                #pragma unroll
                for (int mi = 0; mi < 4; ++mi)
                    aU[mi][mt] = MFMA(a, BU[mi][ks], aU[mi][mt]);
            }
        #pragma unroll
        for (int mi = 0; mi < 4; ++mi)
            #pragma unroll
            for (int mt = 0; mt < 2; ++mt) {
                u2[mi][mt][0] = pack2(aU[mi][mt][0], aU[mi][mt][1]);
                u2[mi][mt][1] = pack2(aU[mi][mt][2], aU[mi][mt][3]);
            }
    }
    {   // Wh B-frags -> LDS (frees 16 regs vs keeping a 4th W array live)
        bf16x8 WT[4];
        loadB(wbuf, 8, nt, lane, WT);
        #pragma unroll
        for (int ks = 0; ks < 4; ++ks)
            *(bf16x8*)(whb + nt * 2048 + ks * 512 + lane * 8) = WT[ks];
    }
    bf16x8 Wz[4], Wg[4], Wr[4];
    loadB(wbuf, 5, nt, lane, Wz);
    loadB(wbuf, 6, nt, lane, Wg);
    loadB(wbuf, 7, nt, lane, Wr);
    __syncthreads();   // S1 + Wh-LDS visible; xt reads complete

    const unsigned short* whl = whb + nt * 2048;
    unsigned short* scur = sb0;
    unsigned short* snxt = sb1;

    // ---- recurrent layers: {Z,G,R fused} -> B1 -> {H, epilogue} -> B2 ----
    for (int l = 0; l < lcount; ++l) {
        f32x4 az[2], ag[2], ar[2];
        #pragma unroll
        for (int mt = 0; mt < 2; ++mt) {
            az[mt] = (f32x4){bf_lo(u2[0][mt][0]), bf_hi(u2[0][mt][0]),
                             bf_lo(u2[0][mt][1]), bf_hi(u2[0][mt][1])};
            ag[mt] = (f32x4){bf_lo(u2[1][mt][0]), bf_hi(u2[1][mt][0]),
                             bf_lo(u2[1][mt][1]), bf_hi(u2[1][mt][1])};
            ar[mt] = (f32x4){bf_lo(u2[2][mt][0]), bf_hi(u2[2][mt][0]),
                             bf_lo(u2[2][mt][1]), bf_hi(u2[2][mt][1])};
        }
        #pragma unroll
        for (int ks = 0; ks < 4; ++ks)
            #pragma unroll
            for (int mt = 0; mt < 2; ++mt) {
                bf16x8 a = *(const bf16x8*)(scur + mt * 2048 + ks * 512 + aoff);
                az[mt] = MFMA(a, Wz[ks], az[mt]);
                ag[mt] = MFMA(a, Wg[ks], ag[mt]);
                ar[mt] = MFMA(a, Wr[ks], ar[mt]);
            }
        // R epilogue: S*R -> xtb (swizzled b16 stores, conflict-free)
        #pragma unroll
        for (int mt = 0; mt < 2; ++mt) {
            float q0 = sreg4[mt][0] * tanh_a(ar[mt][0]);
            float q1 = sreg4[mt][1] * tanh_a(ar[mt][1]);
            float q2 = sreg4[mt][2] * tanh_a(ar[mt][2]);
            float q3 = sreg4[mt][3] * tanh_a(ar[mt][3]);
            unsigned q01 = pack2(q0, q1), q23 = pack2(q2, q3);
            xtb[mt * 2048 + st0] = (unsigned short)q01;
            xtb[mt * 2048 + st1] = (unsigned short)(q01 >> 16);
            xtb[mt * 2048 + st2] = (unsigned short)q23;
            xtb[mt * 2048 + st3] = (unsigned short)(q23 >> 16);
        }
        __syncthreads();   // B1: S*R visible

        // H = uh + (S*R)@Wsh ; Z/G finishers overlap the H ds_reads
        f32x4 ah[2];
        #pragma unroll
        for (int mt = 0; mt < 2; ++mt)
            ah[mt] = (f32x4){bf_lo(u2[3][mt][0]), bf_hi(u2[3][mt][0]),
                             bf_lo(u2[3][mt][1]), bf_hi(u2[3][mt][1])};
        #pragma unroll
        for (int ks = 0; ks < 4; ++ks) {
            bf16x8 wh = *(const bf16x8*)(whl + ks * 512 + lane * 8);
            #pragma unroll
            for (int mt = 0; mt < 2; ++mt) {
                bf16x8 a = *(const bf16x8*)(xtb + mt * 2048 + ks * 512 + aoff);
                ah[mt] = MFMA(a, wh, ah[mt]);
            }
        }
        bool lastl = (l == lcount - 1);
        #pragma unroll
        for (int mt = 0; mt < 2; ++mt) {
            f32x4 o;
            #pragma unroll
            for (int e = 0; e < 4; ++e) {
                float zz = __builtin_fmaf(-2.0f, rcp1p(az[mt][e]), 1.0f); // Z
                float tp = zz * sreg4[mt][e];                             // Z*S
                float gp = 2.0f * rcp1p(ag[mt][e]);                       // 1-G
                o[e] = __builtin_fmaf(gp, ah[mt][e], tp);
            }
            sreg4[mt] = o;
            if (!lastl) {
                unsigned p01 = pack2(o[0], o[1]), p23 = pack2(o[2], o[3]);
                snxt[mt * 2048 + st0] = (unsigned short)p01;
                snxt[mt * 2048 + st1] = (unsigned short)(p01 >> 16);
                snxt[mt * 2048 + st2] = (unsigned short)p23;
                snxt[mt * 2048 + st3] = (unsigned short)(p23 >> 16);
            }
        }
        __syncthreads();   // B2: new S visible; this layer's LDS reads done
        unsigned short* tswp = scur; scur = snxt; snxt = tswp;
    }

    // ---- final: y = out @ Wf + Wf_b (per-wave partials, combine via LDS) ----
    // Safe: the last barrier (B2 or projection sync) ended all xtb reads.
    float* yp = (float*)lds;
    float wfv = Wf_w[col];
    #pragma unroll
    for (int mt = 0; mt < 2; ++mt)
        #pragma unroll
        for (int e = 0; e < 4; ++e) {
            float p = sreg4[mt][e] * wfv;
            p += __shfl_xor(p, 1);
            p += __shfl_xor(p, 2);
            p += __shfl_xor(p, 4);
            p += __shfl_xor(p, 8);
            if (l15 == 0) yp[(mt * 16 + quad * 4 + e) * 8 + wv] = p;
        }
    __syncthreads();
    if (tid < BROWS) {
        const float* r8 = yp + tid * 8;
        float r = ((r8[0] + r8[1]) + (r8[2] + r8[3])) +
                  ((r8[4] + r8[5]) + (r8[6] + r8[7])) + Wf_b[0];
        y[(size_t)blk * BROWS + tid] = r;
    }
}

extern "C" void kernel_launch(void* const* d_in, const int* in_sizes, int n_in,
                              void* d_out, int out_size, void* d_ws, size_t ws_size,
                              hipStream_t stream) {
    const float* x     = (const float*)d_in[0];
    const float* t     = (const float*)d_in[1];
    const float* Sw_w  = (const float*)d_in[2];
    const float* Sw_b  = (const float*)d_in[3];
    const float* Uz_w  = (const float*)d_in[4];
    const float* Uz_b  = (const float*)d_in[5];
    const float* Wsz_w = (const float*)d_in[6];
    const float* Wsz_b = (const float*)d_in[7];
    const float* Ug_w  = (const float*)d_in[8];
    const float* Ug_b  = (const float*)d_in[9];
    const float* Wsg_w = (const float*)d_in[10];
    const float* Wsg_b = (const float*)d_in[11];
    const float* Ur_w  = (const float*)d_in[12];
    const float* Ur_b  = (const float*)d_in[13];
    const float* Wsr_w = (const float*)d_in[14];
    const float* Wsr_b = (const float*)d_in[15];
    const float* Uh_w  = (const float*)d_in[16];
    const float* Uh_b  = (const float*)d_in[17];
    const float* Wsh_w = (const float*)d_in[18];
    const float* Wsh_b = (const float*)d_in[19];
    const float* Wf_w  = (const float*)d_in[20];
    const float* Wf_b  = (const float*)d_in[21];
    const int*   nl    = (const int*)d_in[22];

    unsigned short* wbuf = (unsigned short*)d_ws;
    float* y = (float*)d_out;
    const int B = in_sizes[0] / XD;

    prep_kernel<<<dim3((NMAT * 4096 + 255) / 256), dim3(256), 0, stream>>>(
        Sw_w, Uz_w, Ug_w, Ur_w, Uh_w, Wsz_w, Wsg_w, Wsr_w, Wsh_w, wbuf);

    dgm_main<<<dim3(B / BROWS), dim3(512), 0, stream>>>(
        x, t, wbuf, Sw_b, Uz_b, Ug_b, Ur_b, Uh_b,
        Wsz_b, Wsg_b, Wsr_b, Wsh_b, Wf_w, Wf_b, nl, y);
}